// Round 10
// baseline (210.040 us; speedup 1.0000x reference)
//
#include <hip/hip_runtime.h>
#include <hip/hip_bf16.h>

#define N_NODES 50000
#define N_EDGES 500000
#define HDIM 128
#define HEADS 3
#define BB 512
#define LL 10
#define NEG_SLOPE 0.2f

typedef __hip_bfloat16 bf16;
typedef unsigned char fp8t;
typedef __bf16 v8bf __attribute__((ext_vector_type(8)));
typedef float f32x4 __attribute__((ext_vector_type(4)));

// ---------------- utility ----------------

__global__ void k_zero2(int* a, int na, int* b, int nb, int* c){
  int i = blockIdx.x*256 + threadIdx.x;
  if(i < na) a[i] = 0;
  if(i < nb) b[i] = 0;
  if(i == 0) c[0] = 0;
}

__global__ void k_hist(const int* __restrict__ dst, int* __restrict__ cnt, int E){
  int e = blockIdx.x*256 + threadIdx.x;
  if(e < E) atomicAdd(&cnt[dst[e]], 1);
}

// f32 -> bf16, 8 elems/thread
__global__ void k_cvt(const float* __restrict__ in, bf16* __restrict__ o, int n){
  int i = (blockIdx.x*256 + threadIdx.x)*8;
  if(i < n){
    f32x4 lo = *reinterpret_cast<const f32x4*>(in + i);
    f32x4 hi = *reinterpret_cast<const f32x4*>(in + i + 4);
    v8bf v;
    #pragma unroll
    for(int j = 0; j < 4; ++j){ v[j] = (__bf16)lo[j]; v[4+j] = (__bf16)hi[j]; }
    *reinterpret_cast<v8bf*>(o + i) = v;
  }
}

// ---------------- hierarchical scan ----------------

#define SCAN_TILE 2048
#define SCAN_NB ((N_NODES + SCAN_TILE - 1)/SCAN_TILE)   // 25

__global__ __launch_bounds__(256) void k_scan_part(const int* __restrict__ cnt,
                                                   int* __restrict__ bsum){
  int b = blockIdx.x, tid = threadIdx.x;
  int i0 = b*SCAN_TILE + tid*8;
  int s = 0;
  #pragma unroll
  for(int j = 0; j < 8; ++j){ int i = i0 + j; s += (i < N_NODES) ? cnt[i] : 0; }
  for(int m = 32; m; m >>= 1) s += __shfl_xor(s, m);
  __shared__ int ws[4];
  if((tid & 63) == 0) ws[tid >> 6] = s;
  __syncthreads();
  if(tid == 0) bsum[b] = ws[0] + ws[1] + ws[2] + ws[3];
}

__global__ __launch_bounds__(64) void k_scan_top(int* __restrict__ bsum, int nb){
  int tid = threadIdx.x;
  int v = (tid < nb) ? bsum[tid] : 0;
  for(int s = 1; s < 64; s <<= 1){
    int t = __shfl_up(v, s);
    if(tid >= s) v += t;
  }
  if(tid < nb) bsum[tid] = v;
}

__global__ __launch_bounds__(256) void k_scan_write(int* __restrict__ cnt,
                                                    const int* __restrict__ bsum,
                                                    int* __restrict__ offs){
  int b = blockIdx.x, tid = threadIdx.x;
  int lane = tid & 63, wv = tid >> 6;
  int i0 = b*SCAN_TILE + tid*8;
  int v[8]; int s = 0;
  #pragma unroll
  for(int j = 0; j < 8; ++j){
    int i = i0 + j;
    v[j] = (i < N_NODES) ? cnt[i] : 0;
    s += v[j];
  }
  #pragma unroll
  for(int j = 0; j < 8; ++j){ int i = i0 + j; if(i < N_NODES) cnt[i] = 0; }
  int incl = s;
  for(int sh = 1; sh < 64; sh <<= 1){
    int t = __shfl_up(incl, sh);
    if(lane >= sh) incl += t;
  }
  __shared__ int wtot[4];
  if(lane == 63) wtot[wv] = incl;
  __syncthreads();
  int woff = 0;
  for(int w = 0; w < wv; ++w) woff += wtot[w];
  int excl = woff + incl - s;
  int run = ((b > 0) ? bsum[b-1] : 0) + excl;
  #pragma unroll
  for(int j = 0; j < 8; ++j){
    int i = i0 + j;
    run += v[j];
    if(i < N_NODES) offs[i+1] = run;
  }
  if(b == 0 && tid == 0) offs[0] = 0;
}

__global__ void k_scatter(const int* __restrict__ src, const int* __restrict__ dst,
                          const int* __restrict__ offs, int* __restrict__ cur,
                          int* __restrict__ csr, int E){
  int e = blockIdx.x*256 + threadIdx.x;
  if(e < E){
    int d = dst[e];
    int p = offs[d] + atomicAdd(&cur[d], 1);
    if(p >= 0 && p < E) csr[p] = src[e];
  }
}

// ---------------- mark + list of nodes consumed by layer 2 ----------------

__global__ __launch_bounds__(64) void k_mark(const int* __restrict__ nid,
                                             const int* __restrict__ offs,
                                             const int* __restrict__ csr,
                                             unsigned char* __restrict__ mark){
  unsigned n = (unsigned)nid[blockIdx.x];
  if(n >= N_NODES) return;
  if(threadIdx.x == 0) mark[n] = 1;
  int o0 = offs[n], o1 = offs[n+1];
  for(int j = o0 + (int)threadIdx.x; j < o1; j += 64){
    unsigned s = (unsigned)csr[j];
    if(s < N_NODES) mark[s] = 1;
  }
}

__global__ void k_mklist(const unsigned char* __restrict__ mark,
                         int* __restrict__ list, int* __restrict__ cnt){
  int i = blockIdx.x*256 + threadIdx.x;
  if(i < N_NODES && mark[i]){
    int p = atomicAdd(cnt, 1);
    list[p] = i;
  }
}

// ---------------- W transpose+convert ----------------

__global__ void k_wt(const float* __restrict__ W, bf16* __restrict__ Wt){
  int i = blockIdx.x*256 + threadIdx.x;
  if(i < HEADS*HDIM*HDIM){
    int n = i >> 7, k = i & 127;
    Wt[i] = __float2bfloat16(W[k*(HEADS*HDIM) + n]);
  }
}

// ---------------- GEMM + fused el/er + fp8 feat write ----------------
// LIST=1: rows are list[0..*pcnt); blocks past *pcnt exit.

template<int LIST>
__global__ __launch_bounds__(256) void k_gemm(const bf16* __restrict__ A,
                                              const bf16* __restrict__ Wt,
                                              const float* __restrict__ al,
                                              const float* __restrict__ ar,
                                              fp8t* __restrict__ feat8,
                                              float* __restrict__ el4,
                                              float* __restrict__ er4,
                                              const int* __restrict__ list,
                                              const int* __restrict__ pcnt,
                                              int M){
  int Meff = LIST ? pcnt[0] : M;
  if(blockIdx.x*64 >= Meff) return;
  int tid  = threadIdx.x;
  int wave = tid >> 6, lane = tid & 63;
  int wr = wave >> 1, wc = wave & 1;
  int row0 = blockIdx.x*64 + wr*32;
  int col0 = blockIdx.y*128 + wc*64;
  int l15 = lane & 15, lhi = lane >> 4;

  v8bf a[4][2], b[4][4];
  int nodeA[2];
  #pragma unroll
  for(int mi = 0; mi < 2; ++mi){
    int r = row0 + mi*16 + l15;
    if(r >= Meff) r = Meff - 1;
    nodeA[mi] = LIST ? list[r] : r;
  }
  #pragma unroll
  for(int kk = 0; kk < 4; ++kk){
    int kb = kk*32 + lhi*8;
    #pragma unroll
    for(int mi = 0; mi < 2; ++mi)
      a[kk][mi] = *reinterpret_cast<const v8bf*>(A + (size_t)nodeA[mi]*HDIM + kb);
    #pragma unroll
    for(int ni = 0; ni < 4; ++ni){
      int c = col0 + ni*16 + l15;
      b[kk][ni] = *reinterpret_cast<const v8bf*>(Wt + (size_t)c*HDIM + kb);
    }
  }

  f32x4 acc[2][4] = {};
  #pragma unroll
  for(int kk = 0; kk < 4; ++kk)
    #pragma unroll
    for(int mi = 0; mi < 2; ++mi)
      #pragma unroll
      for(int ni = 0; ni < 4; ++ni)
        acc[mi][ni] = __builtin_amdgcn_mfma_f32_16x16x32_bf16(a[kk][mi], b[kk][ni],
                                                              acc[mi][ni], 0, 0, 0);

  const float* alh = al + blockIdx.y*HDIM;
  const float* arh = ar + blockIdx.y*HDIM;
  float alv[4], arv[4];
  #pragma unroll
  for(int ni = 0; ni < 4; ++ni){
    int d = wc*64 + ni*16 + l15;
    alv[ni] = alh[d]; arv[ni] = arh[d];
  }
  __shared__ float red[2][64][2];
  __shared__ int4 tile4[512];
  fp8t* tile8 = (fp8t*)tile4;

  #pragma unroll
  for(int mi = 0; mi < 2; ++mi){
    #pragma unroll
    for(int j = 0; j < 4; ++j){
      float pe = 0.f, pr = 0.f;
      #pragma unroll
      for(int ni = 0; ni < 4; ++ni){
        pe += acc[mi][ni][j]*alv[ni];
        pr += acc[mi][ni][j]*arv[ni];
      }
      for(int k = 8; k; k >>= 1){ pe += __shfl_xor(pe, k); pr += __shfl_xor(pr, k); }
      int row_l = wr*32 + mi*16 + lhi*4 + j;
      if(l15 == 0){ red[wc][row_l][0] = pe; red[wc][row_l][1] = pr; }
    }
  }
  #pragma unroll
  for(int mi = 0; mi < 2; ++mi)
    #pragma unroll
    for(int j = 0; j < 4; ++j){
      int row_l = wr*32 + mi*16 + lhi*4 + j;
      #pragma unroll
      for(int ni = 0; ni < 4; ++ni){
        float x = acc[mi][ni][j];
        unsigned bb = (unsigned)__builtin_amdgcn_cvt_pk_fp8_f32(x, x, 0, false) & 0xFFu;
        tile8[row_l*128 + wc*64 + ni*16 + l15] = (fp8t)bb;
      }
    }
  __syncthreads();

  if(tid < 64){
    int r = blockIdx.x*64 + tid;
    if(r < Meff){
      int node = LIST ? list[r] : r;
      el4[(size_t)node*4 + blockIdx.y] = red[0][tid][0] + red[1][tid][0];
      er4[(size_t)node*4 + blockIdx.y] = red[0][tid][1] + red[1][tid][1];
    }
  }
  #pragma unroll
  for(int pass = 0; pass < 2; ++pass){
    int off = pass*4096 + tid*16;
    int row_l = off >> 7, col = off & 127;
    int r = blockIdx.x*64 + row_l;
    if(r < Meff){
      int node = LIST ? list[r] : r;
      *reinterpret_cast<int4*>(feat8 + (size_t)node*(HEADS*HDIM) + blockIdx.y*HDIM + col) =
          tile4[off >> 4];
    }
  }
}

// ---------------- aggregation: one WAVE per dst node (no LDS, no barriers) ----
// No-max softmax (logits bounded); unnormalized weights + per-lane denominator.
// Lane owns feat dwords {lane, lane+64} (96 dwords = 3 heads x 32 dwords).

__device__ __forceinline__ float lrelu(float x){ return x > 0.f ? x : NEG_SLOPE*x; }

#define SEQ_SZ   (BB*LL*4*HDIM)
#define SEQR_OFF SEQ_SZ
#define SEQR_SZ  (BB*LL*3*HDIM)
#define SH_OFF   (SEQ_SZ + SEQR_SZ)

template<int USE_LIST, int FUSED, int USE_MARK>
__global__ __launch_bounds__(256) void k_agg(const fp8t* __restrict__ feat8,
                                             const float* __restrict__ el4,
                                             const float* __restrict__ er4,
                                             const float* __restrict__ bias,
                                             const int* __restrict__ offs,
                                             const int* __restrict__ csr,
                                             const int* __restrict__ list,
                                             const unsigned char* __restrict__ mark,
                                             bf16* __restrict__ h1,
                                             const float* __restrict__ ent_e,
                                             const float* __restrict__ rel_e,
                                             const float* __restrict__ glob,
                                             const float* __restrict__ sht,
                                             const int* __restrict__ s_tem,
                                             const int* __restrict__ r_tem,
                                             float* __restrict__ out,
                                             int total){
  int widx = blockIdx.x*4 + (threadIdx.x >> 6);
  int lane = threadIdx.x & 63;
  if(widx >= total) return;
  int n = USE_LIST ? list[widx] : widx;
  if(USE_MARK){ if(!mark[n]) return; }
  int o0 = offs[n];
  int deg = offs[n+1] - o0;
  if(deg < 0 || deg > N_EDGES) deg = 0;
  float4 erv = *reinterpret_cast<const float4*>(er4 + (size_t)n*4);

  // accumulators: dword A = lane (head lane>>5), dword B = lane+64 (head 2, lane<32)
  float aA0=0.f,aA1=0.f,aA2=0.f,aA3=0.f, dhA=0.f;
  float aB0=0.f,aB1=0.f,aB2=0.f,aB3=0.f, dhB=0.f;
  int headA = lane >> 5;

  for(int base = 0; base < deg; base += 64){
    int cn = min(64, deg - base);
    float e0 = 0.f, e1 = 0.f, e2 = 0.f; int s = 0;
    if(lane < cn){
      unsigned su = (unsigned)csr[o0 + base + lane];
      if(su >= N_NODES) su = 0;
      s = (int)su;
      float4 elv = *reinterpret_cast<const float4*>(el4 + (size_t)su*4);
      e0 = __expf(lrelu(elv.x + erv.x));
      e1 = __expf(lrelu(elv.y + erv.y));
      e2 = __expf(lrelu(elv.z + erv.z));
    }
    for(int i = 0; i < cn; ++i){
      int  si = __shfl(s,  i);
      float b0 = __shfl(e0, i);
      float b1 = __shfl(e1, i);
      float b2 = __shfl(e2, i);
      const fp8t* fr = feat8 + (size_t)si*(HEADS*HDIM);
      unsigned uA = *reinterpret_cast<const unsigned*>(fr + lane*4);
      float alA = headA ? b1 : b0;
      dhA += alA;
      aA0 += alA*__builtin_amdgcn_cvt_f32_fp8((int)uA, 0);
      aA1 += alA*__builtin_amdgcn_cvt_f32_fp8((int)uA, 1);
      aA2 += alA*__builtin_amdgcn_cvt_f32_fp8((int)uA, 2);
      aA3 += alA*__builtin_amdgcn_cvt_f32_fp8((int)uA, 3);
      if(lane < 32){
        unsigned uB = *reinterpret_cast<const unsigned*>(fr + 256 + lane*4);
        dhB += b2;
        aB0 += b2*__builtin_amdgcn_cvt_f32_fp8((int)uB, 0);
        aB1 += b2*__builtin_amdgcn_cvt_f32_fp8((int)uB, 1);
        aB2 += b2*__builtin_amdgcn_cvt_f32_fp8((int)uB, 2);
        aB3 += b2*__builtin_amdgcn_cvt_f32_fp8((int)uB, 3);
      }
    }
  }

  float invA = (dhA > 0.f) ? 1.f/dhA : 0.f;
  float invB = (dhB > 0.f) ? 1.f/dhB : 0.f;
  float nA0 = aA0*invA, nA1 = aA1*invA, nA2 = aA2*invA, nA3 = aA3*invA;
  // head1 values live in lanes 32..63; pull them to lanes 0..31
  float x0 = __shfl(nA0, lane + 32);
  float x1 = __shfl(nA1, lane + 32);
  float x2 = __shfl(nA2, lane + 32);
  float x3 = __shfl(nA3, lane + 32);
  if(lane < 32){
    int m = lane;                       // dim group: dims 4m..4m+3
    float4 bs0 = *reinterpret_cast<const float4*>(bias + 4*m);
    float4 bs1 = *reinterpret_cast<const float4*>(bias + HDIM + 4*m);
    float4 bs2 = *reinterpret_cast<const float4*>(bias + 2*HDIM + 4*m);
    float4 r;
    r.x = (nA0 + x0 + aB0*invB + bs0.x + bs1.x + bs2.x)*(1.f/3.f);
    r.y = (nA1 + x1 + aB1*invB + bs0.y + bs1.y + bs2.y)*(1.f/3.f);
    r.z = (nA2 + x2 + aB2*invB + bs0.z + bs1.z + bs2.z)*(1.f/3.f);
    r.w = (nA3 + x3 + aB3*invB + bs0.w + bs1.w + bs2.w)*(1.f/3.f);
    if(FUSED){
      int p = widx, bb = p/LL;
      float4 ent = *reinterpret_cast<const float4*>(ent_e + (size_t)s_tem[bb]*HDIM + 4*m);
      float4 rel = *reinterpret_cast<const float4*>(rel_e + (size_t)r_tem[bb]*HDIM + 4*m);
      float4 gl  = *reinterpret_cast<const float4*>(glob + (size_t)p*HDIM + 4*m);
      float* so = out + (size_t)p*(4*HDIM) + 4*m;
      *reinterpret_cast<float4*>(so)            = r;
      *reinterpret_cast<float4*>(so + HDIM)     = ent;
      *reinterpret_cast<float4*>(so + 2*HDIM)   = rel;
      *reinterpret_cast<float4*>(so + 3*HDIM)   = gl;
      float* ro = out + SEQR_OFF + (size_t)p*(3*HDIM) + 4*m;
      *reinterpret_cast<float4*>(ro)            = r;
      *reinterpret_cast<float4*>(ro + HDIM)     = ent;
      *reinterpret_cast<float4*>(ro + 2*HDIM)   = gl;
      if(m == 0) out[SH_OFF + p] = sht[p];
    } else {
      bf16 t0 = __float2bfloat16(r.x), t1 = __float2bfloat16(r.y);
      bf16 t2 = __float2bfloat16(r.z), t3 = __float2bfloat16(r.w);
      ushort4 hv;
      hv.x = *reinterpret_cast<unsigned short*>(&t0);
      hv.y = *reinterpret_cast<unsigned short*>(&t1);
      hv.z = *reinterpret_cast<unsigned short*>(&t2);
      hv.w = *reinterpret_cast<unsigned short*>(&t3);
      *reinterpret_cast<ushort4*>(h1 + (size_t)n*HDIM + 4*m) = hv;
    }
  }
}

// ---------------- launch ----------------

extern "C" void kernel_launch(void* const* d_in, const int* in_sizes, int n_in,
                              void* d_out, int out_size, void* d_ws, size_t ws_size,
                              hipStream_t stream){
  const float* node_feat = (const float*)d_in[0];
  const float* W1        = (const float*)d_in[1];
  const float* attn_l1   = (const float*)d_in[2];
  const float* attn_r1   = (const float*)d_in[3];
  const float* b1        = (const float*)d_in[4];
  const float* W2        = (const float*)d_in[5];
  const float* attn_l2   = (const float*)d_in[6];
  const float* attn_r2   = (const float*)d_in[7];
  const float* b2        = (const float*)d_in[8];
  const float* ent_emb   = (const float*)d_in[9];
  const float* rel_emb   = (const float*)d_in[10];
  const float* glob      = (const float*)d_in[11];
  const float* sht       = (const float*)d_in[12];
  const int*  e_src      = (const int*)d_in[13];
  const int*  e_dst      = (const int*)d_in[14];
  const int*  nid        = (const int*)d_in[15];
  const int*  s_tem      = (const int*)d_in[16];
  const int*  r_tem      = (const int*)d_in[17];
  float* out = (float*)d_out;

  char* ws = (char*)d_ws;
  size_t cur_off = 0;
  auto alloc = [&](size_t bytes)->char*{
    char* r = ws + cur_off;
    cur_off += (bytes + 255) & ~(size_t)255;
    return r;
  };
  fp8t*  feat8 = (fp8t*) alloc((size_t)N_NODES*HEADS*HDIM);
  bf16*  nfb   = (bf16*) alloc((size_t)N_NODES*HDIM*2);
  bf16*  h1    = (bf16*) alloc((size_t)N_NODES*HDIM*2);
  float* el4   = (float*)alloc((size_t)N_NODES*4*4);
  float* er4   = (float*)alloc((size_t)N_NODES*4*4);
  bf16*  wt1   = (bf16*) alloc((size_t)HEADS*HDIM*HDIM*2);
  bf16*  wt2   = (bf16*) alloc((size_t)HEADS*HDIM*HDIM*2);
  int*   offs  = (int*)  alloc((size_t)(N_NODES+1)*4);
  int*   cnt   = (int*)  alloc((size_t)N_NODES*4);
  int*   bsum  = (int*)  alloc((size_t)SCAN_NB*4);
  unsigned char* mark = (unsigned char*)alloc((size_t)N_NODES);
  int*   mlist = (int*)  alloc((size_t)N_NODES*4);
  int*   mcnt  = (int*)  alloc(256);
  int*   csr   = (int*)  alloc((size_t)N_EDGES*4);

  // CSR build; zero cnt + mark + mcnt in one launch
  k_zero2<<<(N_NODES+255)/256, 256, 0, stream>>>(cnt, N_NODES,
                                                 (int*)mark, (N_NODES+3)/4, mcnt);
  k_hist<<<(N_EDGES+255)/256, 256, 0, stream>>>(e_dst, cnt, N_EDGES);
  k_scan_part<<<SCAN_NB, 256, 0, stream>>>(cnt, bsum);
  k_scan_top<<<1, 64, 0, stream>>>(bsum, SCAN_NB);
  k_scan_write<<<SCAN_NB, 256, 0, stream>>>(cnt, bsum, offs);   // also zeroes cnt
  k_scatter<<<(N_EDGES+255)/256, 256, 0, stream>>>(e_src, e_dst, offs, cnt, csr, N_EDGES);
  k_mark<<<BB*LL, 64, 0, stream>>>(nid, offs, csr, mark);
  k_mklist<<<(N_NODES+255)/256, 256, 0, stream>>>(mark, mlist, mcnt);

  // weight transposes + node_feat f32->bf16
  k_wt<<<(HEADS*HDIM*HDIM+255)/256, 256, 0, stream>>>(W1, wt1);
  k_wt<<<(HEADS*HDIM*HDIM+255)/256, 256, 0, stream>>>(W2, wt2);
  k_cvt<<<(N_NODES*HDIM/8+255)/256, 256, 0, stream>>>(node_feat, nfb, N_NODES*HDIM);

  dim3 ggrid((N_NODES + 63)/64, HEADS);

  // Layer 1 (agg only for nodes layer 2 consumes)
  k_gemm<0><<<ggrid, 256, 0, stream>>>(nfb, wt1, attn_l1, attn_r1,
                                       feat8, el4, er4, nullptr, nullptr, N_NODES);
  k_agg<0,0,1><<<(N_NODES+3)/4, 256, 0, stream>>>(feat8, el4, er4, b1, offs, csr,
                                                  nullptr, mark, h1,
                                                  nullptr, nullptr, nullptr, nullptr,
                                                  nullptr, nullptr, nullptr, N_NODES);

  // Layer 2 (gemm over marked rows only; agg fused with assembly)
  k_gemm<1><<<ggrid, 256, 0, stream>>>(h1, wt2, attn_l2, attn_r2,
                                       feat8, el4, er4, mlist, mcnt, N_NODES);
  k_agg<1,1,0><<<(BB*LL+3)/4, 256, 0, stream>>>(feat8, el4, er4, b2, offs, csr,
                                                nid, nullptr, nullptr,
                                                ent_emb, rel_emb, glob, sht,
                                                s_tem, r_tem, out, BB*LL);
}

// Round 11
// 201.691 us; speedup vs baseline: 1.0414x; 1.0414x over previous
//
#include <hip/hip_runtime.h>
#include <hip/hip_bf16.h>

#define N_NODES 50000
#define N_EDGES 500000
#define HDIM 128
#define HEADS 3
#define BB 512
#define LL 10
#define NEG_SLOPE 0.2f

typedef __hip_bfloat16 bf16;
typedef unsigned char fp8t;
typedef __bf16 v8bf __attribute__((ext_vector_type(8)));
typedef float f32x4 __attribute__((ext_vector_type(4)));

// ---------------- utility ----------------

__global__ void k_zero2(int* a, int na, int* b, int nb, int* c){
  int i = blockIdx.x*256 + threadIdx.x;
  if(i < na) a[i] = 0;
  if(i < nb) b[i] = 0;
  if(i == 0) c[0] = 0;
}

__global__ void k_hist(const int* __restrict__ dst, int* __restrict__ cnt, int E){
  int e = blockIdx.x*256 + threadIdx.x;
  if(e < E) atomicAdd(&cnt[dst[e]], 1);
}

// f32 -> bf16, 8 elems/thread
__global__ void k_cvt(const float* __restrict__ in, bf16* __restrict__ o, int n){
  int i = (blockIdx.x*256 + threadIdx.x)*8;
  if(i < n){
    f32x4 lo = *reinterpret_cast<const f32x4*>(in + i);
    f32x4 hi = *reinterpret_cast<const f32x4*>(in + i + 4);
    v8bf v;
    #pragma unroll
    for(int j = 0; j < 4; ++j){ v[j] = (__bf16)lo[j]; v[4+j] = (__bf16)hi[j]; }
    *reinterpret_cast<v8bf*>(o + i) = v;
  }
}

// ---------------- hierarchical scan ----------------

#define SCAN_TILE 2048
#define SCAN_NB ((N_NODES + SCAN_TILE - 1)/SCAN_TILE)   // 25

__global__ __launch_bounds__(256) void k_scan_part(const int* __restrict__ cnt,
                                                   int* __restrict__ bsum){
  int b = blockIdx.x, tid = threadIdx.x;
  int i0 = b*SCAN_TILE + tid*8;
  int s = 0;
  #pragma unroll
  for(int j = 0; j < 8; ++j){ int i = i0 + j; s += (i < N_NODES) ? cnt[i] : 0; }
  for(int m = 32; m; m >>= 1) s += __shfl_xor(s, m);
  __shared__ int ws[4];
  if((tid & 63) == 0) ws[tid >> 6] = s;
  __syncthreads();
  if(tid == 0) bsum[b] = ws[0] + ws[1] + ws[2] + ws[3];
}

__global__ __launch_bounds__(64) void k_scan_top(int* __restrict__ bsum, int nb){
  int tid = threadIdx.x;
  int v = (tid < nb) ? bsum[tid] : 0;
  for(int s = 1; s < 64; s <<= 1){
    int t = __shfl_up(v, s);
    if(tid >= s) v += t;
  }
  if(tid < nb) bsum[tid] = v;
}

__global__ __launch_bounds__(256) void k_scan_write(int* __restrict__ cnt,
                                                    const int* __restrict__ bsum,
                                                    int* __restrict__ offs){
  int b = blockIdx.x, tid = threadIdx.x;
  int lane = tid & 63, wv = tid >> 6;
  int i0 = b*SCAN_TILE + tid*8;
  int v[8]; int s = 0;
  #pragma unroll
  for(int j = 0; j < 8; ++j){
    int i = i0 + j;
    v[j] = (i < N_NODES) ? cnt[i] : 0;
    s += v[j];
  }
  #pragma unroll
  for(int j = 0; j < 8; ++j){ int i = i0 + j; if(i < N_NODES) cnt[i] = 0; }
  int incl = s;
  for(int sh = 1; sh < 64; sh <<= 1){
    int t = __shfl_up(incl, sh);
    if(lane >= sh) incl += t;
  }
  __shared__ int wtot[4];
  if(lane == 63) wtot[wv] = incl;
  __syncthreads();
  int woff = 0;
  for(int w = 0; w < wv; ++w) woff += wtot[w];
  int excl = woff + incl - s;
  int run = ((b > 0) ? bsum[b-1] : 0) + excl;
  #pragma unroll
  for(int j = 0; j < 8; ++j){
    int i = i0 + j;
    run += v[j];
    if(i < N_NODES) offs[i+1] = run;
  }
  if(b == 0 && tid == 0) offs[0] = 0;
}

__global__ void k_scatter(const int* __restrict__ src, const int* __restrict__ dst,
                          const int* __restrict__ offs, int* __restrict__ cur,
                          int* __restrict__ csr, int E){
  int e = blockIdx.x*256 + threadIdx.x;
  if(e < E){
    int d = dst[e];
    int p = offs[d] + atomicAdd(&cur[d], 1);
    if(p >= 0 && p < E) csr[p] = src[e];
  }
}

// ---------------- mark + list of nodes consumed by layer 2 ----------------

__global__ __launch_bounds__(64) void k_mark(const int* __restrict__ nid,
                                             const int* __restrict__ offs,
                                             const int* __restrict__ csr,
                                             unsigned char* __restrict__ mark){
  unsigned n = (unsigned)nid[blockIdx.x];
  if(n >= N_NODES) return;
  if(threadIdx.x == 0) mark[n] = 1;
  int o0 = offs[n], o1 = offs[n+1];
  for(int j = o0 + (int)threadIdx.x; j < o1; j += 64){
    unsigned s = (unsigned)csr[j];
    if(s < N_NODES) mark[s] = 1;
  }
}

__global__ void k_mklist(const unsigned char* __restrict__ mark,
                         int* __restrict__ list, int* __restrict__ cnt){
  int i = blockIdx.x*256 + threadIdx.x;
  if(i < N_NODES && mark[i]){
    int p = atomicAdd(cnt, 1);
    list[p] = i;
  }
}

// ---------------- W transpose+convert ----------------

__global__ void k_wt(const float* __restrict__ W, bf16* __restrict__ Wt){
  int i = blockIdx.x*256 + threadIdx.x;
  if(i < HEADS*HDIM*HDIM){
    int n = i >> 7, k = i & 127;
    Wt[i] = __float2bfloat16(W[k*(HEADS*HDIM) + n]);
  }
}

// ---------------- GEMM + fused el/er + fp8 feat write ----------------
// 1D grid; 24-block groups = 8 xcd-slots x 3 heads so the 3 head-blocks of a
// row-tile land on the SAME XCD within ~16 dispatch slots -> A rows L2-hit.

#define GEMM_NBR 784                       // 782 row-tiles padded to %8==0
#define GEMM_GRID (GEMM_NBR/8*24)          // 2352

template<int LIST>
__global__ __launch_bounds__(256) void k_gemm(const bf16* __restrict__ A,
                                              const bf16* __restrict__ Wt,
                                              const float* __restrict__ al,
                                              const float* __restrict__ ar,
                                              fp8t* __restrict__ feat8,
                                              float* __restrict__ el4,
                                              float* __restrict__ er4,
                                              const int* __restrict__ list,
                                              const int* __restrict__ pcnt,
                                              int M){
  int g = blockIdx.x/24, o = blockIdx.x - g*24;
  int rt = g*8 + (o & 7);
  int head = o >> 3;
  int Meff = LIST ? pcnt[0] : M;
  if(rt*64 >= Meff) return;
  int tid  = threadIdx.x;
  int wave = tid >> 6, lane = tid & 63;
  int wr = wave >> 1, wc = wave & 1;
  int row0 = rt*64 + wr*32;
  int col0 = head*128 + wc*64;
  int l15 = lane & 15, lhi = lane >> 4;

  v8bf a[4][2], b[4][4];
  int nodeA[2];
  #pragma unroll
  for(int mi = 0; mi < 2; ++mi){
    int r = row0 + mi*16 + l15;
    if(r >= Meff) r = Meff - 1;
    nodeA[mi] = LIST ? list[r] : r;
  }
  #pragma unroll
  for(int kk = 0; kk < 4; ++kk){
    int kb = kk*32 + lhi*8;
    #pragma unroll
    for(int mi = 0; mi < 2; ++mi)
      a[kk][mi] = *reinterpret_cast<const v8bf*>(A + (size_t)nodeA[mi]*HDIM + kb);
    #pragma unroll
    for(int ni = 0; ni < 4; ++ni){
      int c = col0 + ni*16 + l15;
      b[kk][ni] = *reinterpret_cast<const v8bf*>(Wt + (size_t)c*HDIM + kb);
    }
  }

  f32x4 acc[2][4] = {};
  #pragma unroll
  for(int kk = 0; kk < 4; ++kk)
    #pragma unroll
    for(int mi = 0; mi < 2; ++mi)
      #pragma unroll
      for(int ni = 0; ni < 4; ++ni)
        acc[mi][ni] = __builtin_amdgcn_mfma_f32_16x16x32_bf16(a[kk][mi], b[kk][ni],
                                                              acc[mi][ni], 0, 0, 0);

  const float* alh = al + head*HDIM;
  const float* arh = ar + head*HDIM;
  float alv[4], arv[4];
  #pragma unroll
  for(int ni = 0; ni < 4; ++ni){
    int d = wc*64 + ni*16 + l15;
    alv[ni] = alh[d]; arv[ni] = arh[d];
  }
  __shared__ float red[2][64][2];
  __shared__ int4 tile4[512];
  fp8t* tile8 = (fp8t*)tile4;

  #pragma unroll
  for(int mi = 0; mi < 2; ++mi){
    #pragma unroll
    for(int j = 0; j < 4; ++j){
      float pe = 0.f, pr = 0.f;
      #pragma unroll
      for(int ni = 0; ni < 4; ++ni){
        pe += acc[mi][ni][j]*alv[ni];
        pr += acc[mi][ni][j]*arv[ni];
      }
      for(int k = 8; k; k >>= 1){ pe += __shfl_xor(pe, k); pr += __shfl_xor(pr, k); }
      int row_l = wr*32 + mi*16 + lhi*4 + j;
      if(l15 == 0){ red[wc][row_l][0] = pe; red[wc][row_l][1] = pr; }
    }
  }
  #pragma unroll
  for(int mi = 0; mi < 2; ++mi)
    #pragma unroll
    for(int j = 0; j < 4; ++j){
      int row_l = wr*32 + mi*16 + lhi*4 + j;
      #pragma unroll
      for(int ni = 0; ni < 4; ++ni){
        float x = acc[mi][ni][j];
        unsigned bb = (unsigned)__builtin_amdgcn_cvt_pk_fp8_f32(x, x, 0, false) & 0xFFu;
        tile8[row_l*128 + wc*64 + ni*16 + l15] = (fp8t)bb;
      }
    }
  __syncthreads();

  if(tid < 64){
    int r = rt*64 + tid;
    if(r < Meff){
      int node = LIST ? list[r] : r;
      el4[(size_t)node*4 + head] = red[0][tid][0] + red[1][tid][0];
      er4[(size_t)node*4 + head] = red[0][tid][1] + red[1][tid][1];
    }
  }
  #pragma unroll
  for(int pass = 0; pass < 2; ++pass){
    int off = pass*4096 + tid*16;
    int row_l = off >> 7, col = off & 127;
    int r = rt*64 + row_l;
    if(r < Meff){
      int node = LIST ? list[r] : r;
      *reinterpret_cast<int4*>(feat8 + (size_t)node*(HEADS*HDIM) + head*HDIM + col) =
          tile4[off >> 4];
    }
  }
}

// ---------------- aggregation: one block (128 thr) per dst node ----------------
// No-max softmax; unnormalized weights + in-loop denominator; accumulate loop
// manually unrolled x4 for memory-level parallelism (4 gathers in flight).

__device__ __forceinline__ float lrelu(float x){ return x > 0.f ? x : NEG_SLOPE*x; }

#define AGG_CHUNK 128
#define SEQ_SZ   (BB*LL*4*HDIM)
#define SEQR_OFF SEQ_SZ
#define SEQR_SZ  (BB*LL*3*HDIM)
#define SH_OFF   (SEQ_SZ + SEQR_SZ)

template<int USE_LIST, int FUSED, int USE_MARK>
__global__ __launch_bounds__(128) void k_agg(const fp8t* __restrict__ feat8,
                                             const float* __restrict__ el4,
                                             const float* __restrict__ er4,
                                             const float* __restrict__ bias,
                                             const int* __restrict__ offs,
                                             const int* __restrict__ csr,
                                             const int* __restrict__ list,
                                             const unsigned char* __restrict__ mark,
                                             bf16* __restrict__ h1,
                                             const float* __restrict__ ent_e,
                                             const float* __restrict__ rel_e,
                                             const float* __restrict__ glob,
                                             const float* __restrict__ sht,
                                             const int* __restrict__ s_tem,
                                             const int* __restrict__ r_tem,
                                             float* __restrict__ out){
  int bid = blockIdx.x;
  int n = USE_LIST ? list[bid] : bid;
  if(USE_MARK){ if(!mark[n]) return; }
  int tid = threadIdx.x;
  __shared__ float s_alpha[AGG_CHUNK][4];
  __shared__ int   s_src[AGG_CHUNK];
  __shared__ float s_facc[HEADS*HDIM];
  int o0 = offs[n];
  int deg = offs[n+1] - o0;
  if(deg < 0 || deg > N_EDGES) deg = 0;
  float4 erv = *reinterpret_cast<const float4*>(er4 + (size_t)n*4);

  float a0 = 0.f, a1 = 0.f, a2 = 0.f, a3 = 0.f, dh = 0.f;
  int head = tid >> 5;
  for(int base = 0; base < deg; base += AGG_CHUNK){
    int cn = min(AGG_CHUNK, deg - base);
    if(base) __syncthreads();
    if(tid < cn){
      unsigned su = (unsigned)csr[o0 + base + tid];
      if(su >= N_NODES) su = 0;
      float4 elv = *reinterpret_cast<const float4*>(el4 + (size_t)su*4);
      s_src[tid] = (int)su;
      s_alpha[tid][0] = __expf(lrelu(elv.x + erv.x));
      s_alpha[tid][1] = __expf(lrelu(elv.y + erv.y));
      s_alpha[tid][2] = __expf(lrelu(elv.z + erv.z));
    }
    __syncthreads();
    if(tid < 96){
      int i = 0;
      for(; i + 4 <= cn; i += 4){
        unsigned u0 = *reinterpret_cast<const unsigned*>(
            feat8 + (size_t)s_src[i+0]*(HEADS*HDIM) + tid*4);
        unsigned u1 = *reinterpret_cast<const unsigned*>(
            feat8 + (size_t)s_src[i+1]*(HEADS*HDIM) + tid*4);
        unsigned u2 = *reinterpret_cast<const unsigned*>(
            feat8 + (size_t)s_src[i+2]*(HEADS*HDIM) + tid*4);
        unsigned u3 = *reinterpret_cast<const unsigned*>(
            feat8 + (size_t)s_src[i+3]*(HEADS*HDIM) + tid*4);
        float al0 = s_alpha[i+0][head];
        float al1 = s_alpha[i+1][head];
        float al2 = s_alpha[i+2][head];
        float al3 = s_alpha[i+3][head];
        dh += al0 + al1 + al2 + al3;
        a0 += al0*__builtin_amdgcn_cvt_f32_fp8((int)u0, 0)
            + al1*__builtin_amdgcn_cvt_f32_fp8((int)u1, 0)
            + al2*__builtin_amdgcn_cvt_f32_fp8((int)u2, 0)
            + al3*__builtin_amdgcn_cvt_f32_fp8((int)u3, 0);
        a1 += al0*__builtin_amdgcn_cvt_f32_fp8((int)u0, 1)
            + al1*__builtin_amdgcn_cvt_f32_fp8((int)u1, 1)
            + al2*__builtin_amdgcn_cvt_f32_fp8((int)u2, 1)
            + al3*__builtin_amdgcn_cvt_f32_fp8((int)u3, 1);
        a2 += al0*__builtin_amdgcn_cvt_f32_fp8((int)u0, 2)
            + al1*__builtin_amdgcn_cvt_f32_fp8((int)u1, 2)
            + al2*__builtin_amdgcn_cvt_f32_fp8((int)u2, 2)
            + al3*__builtin_amdgcn_cvt_f32_fp8((int)u3, 2);
        a3 += al0*__builtin_amdgcn_cvt_f32_fp8((int)u0, 3)
            + al1*__builtin_amdgcn_cvt_f32_fp8((int)u1, 3)
            + al2*__builtin_amdgcn_cvt_f32_fp8((int)u2, 3)
            + al3*__builtin_amdgcn_cvt_f32_fp8((int)u3, 3);
      }
      for(; i < cn; ++i){
        unsigned u = *reinterpret_cast<const unsigned*>(
            feat8 + (size_t)s_src[i]*(HEADS*HDIM) + tid*4);
        float al = s_alpha[i][head];
        dh += al;
        a0 += al*__builtin_amdgcn_cvt_f32_fp8((int)u, 0);
        a1 += al*__builtin_amdgcn_cvt_f32_fp8((int)u, 1);
        a2 += al*__builtin_amdgcn_cvt_f32_fp8((int)u, 2);
        a3 += al*__builtin_amdgcn_cvt_f32_fp8((int)u, 3);
      }
    }
  }
  if(tid < 96){
    float inv = (dh > 0.f) ? 1.f/dh : 0.f;
    float4 w; w.x = a0*inv; w.y = a1*inv; w.z = a2*inv; w.w = a3*inv;
    *reinterpret_cast<float4*>(s_facc + tid*4) = w;
  }
  __syncthreads();
  float r = (s_facc[tid] + s_facc[HDIM + tid] + s_facc[2*HDIM + tid]
           + bias[tid] + bias[HDIM + tid] + bias[2*HDIM + tid])*(1.f/3.f);
  if(FUSED){
    int p = bid, b = p/LL, d = tid;
    float ent = ent_e[(size_t)s_tem[b]*HDIM + d];
    float rel = rel_e[(size_t)r_tem[b]*HDIM + d];
    float gl  = glob[(size_t)p*HDIM + d];
    size_t so = (size_t)p*(4*HDIM);
    out[so + d] = r; out[so + HDIM + d] = ent;
    out[so + 2*HDIM + d] = rel; out[so + 3*HDIM + d] = gl;
    size_t ro = SEQR_OFF + (size_t)p*(3*HDIM);
    out[ro + d] = r; out[ro + HDIM + d] = ent; out[ro + 2*HDIM + d] = gl;
    if(d == 0) out[SH_OFF + p] = sht[p];
  } else {
    h1[(size_t)n*HDIM + tid] = __float2bfloat16(r);
  }
}

// ---------------- launch ----------------

extern "C" void kernel_launch(void* const* d_in, const int* in_sizes, int n_in,
                              void* d_out, int out_size, void* d_ws, size_t ws_size,
                              hipStream_t stream){
  const float* node_feat = (const float*)d_in[0];
  const float* W1        = (const float*)d_in[1];
  const float* attn_l1   = (const float*)d_in[2];
  const float* attn_r1   = (const float*)d_in[3];
  const float* b1        = (const float*)d_in[4];
  const float* W2        = (const float*)d_in[5];
  const float* attn_l2   = (const float*)d_in[6];
  const float* attn_r2   = (const float*)d_in[7];
  const float* b2        = (const float*)d_in[8];
  const float* ent_emb   = (const float*)d_in[9];
  const float* rel_emb   = (const float*)d_in[10];
  const float* glob      = (const float*)d_in[11];
  const float* sht       = (const float*)d_in[12];
  const int*  e_src      = (const int*)d_in[13];
  const int*  e_dst      = (const int*)d_in[14];
  const int*  nid        = (const int*)d_in[15];
  const int*  s_tem      = (const int*)d_in[16];
  const int*  r_tem      = (const int*)d_in[17];
  float* out = (float*)d_out;

  char* ws = (char*)d_ws;
  size_t cur_off = 0;
  auto alloc = [&](size_t bytes)->char*{
    char* r = ws + cur_off;
    cur_off += (bytes + 255) & ~(size_t)255;
    return r;
  };
  fp8t*  feat8 = (fp8t*) alloc((size_t)N_NODES*HEADS*HDIM);
  bf16*  nfb   = (bf16*) alloc((size_t)N_NODES*HDIM*2);
  bf16*  h1    = (bf16*) alloc((size_t)N_NODES*HDIM*2);
  float* el4   = (float*)alloc((size_t)N_NODES*4*4);
  float* er4   = (float*)alloc((size_t)N_NODES*4*4);
  bf16*  wt1   = (bf16*) alloc((size_t)HEADS*HDIM*HDIM*2);
  bf16*  wt2   = (bf16*) alloc((size_t)HEADS*HDIM*HDIM*2);
  int*   offs  = (int*)  alloc((size_t)(N_NODES+1)*4);
  int*   cnt   = (int*)  alloc((size_t)N_NODES*4);
  int*   bsum  = (int*)  alloc((size_t)SCAN_NB*4);
  unsigned char* mark = (unsigned char*)alloc((size_t)N_NODES);
  int*   mlist = (int*)  alloc((size_t)N_NODES*4);
  int*   mcnt  = (int*)  alloc(256);
  int*   csr   = (int*)  alloc((size_t)N_EDGES*4);

  // CSR build; zero cnt + mark + mcnt in one launch
  k_zero2<<<(N_NODES+255)/256, 256, 0, stream>>>(cnt, N_NODES,
                                                 (int*)mark, (N_NODES+3)/4, mcnt);
  k_hist<<<(N_EDGES+255)/256, 256, 0, stream>>>(e_dst, cnt, N_EDGES);
  k_scan_part<<<SCAN_NB, 256, 0, stream>>>(cnt, bsum);
  k_scan_top<<<1, 64, 0, stream>>>(bsum, SCAN_NB);
  k_scan_write<<<SCAN_NB, 256, 0, stream>>>(cnt, bsum, offs);   // also zeroes cnt
  k_scatter<<<(N_EDGES+255)/256, 256, 0, stream>>>(e_src, e_dst, offs, cnt, csr, N_EDGES);
  k_mark<<<BB*LL, 64, 0, stream>>>(nid, offs, csr, mark);
  k_mklist<<<(N_NODES+255)/256, 256, 0, stream>>>(mark, mlist, mcnt);

  // weight transposes + node_feat f32->bf16
  k_wt<<<(HEADS*HDIM*HDIM+255)/256, 256, 0, stream>>>(W1, wt1);
  k_wt<<<(HEADS*HDIM*HDIM+255)/256, 256, 0, stream>>>(W2, wt2);
  k_cvt<<<(N_NODES*HDIM/8+255)/256, 256, 0, stream>>>(node_feat, nfb, N_NODES*HDIM);

  // Layer 1 (agg only for nodes layer 2 consumes)
  k_gemm<0><<<GEMM_GRID, 256, 0, stream>>>(nfb, wt1, attn_l1, attn_r1,
                                           feat8, el4, er4, nullptr, nullptr, N_NODES);
  k_agg<0,0,1><<<N_NODES, 128, 0, stream>>>(feat8, el4, er4, b1, offs, csr,
                                            nullptr, mark, h1,
                                            nullptr, nullptr, nullptr, nullptr,
                                            nullptr, nullptr, nullptr);

  // Layer 2 (gemm over marked rows only; agg fused with assembly)
  k_gemm<1><<<GEMM_GRID, 256, 0, stream>>>(h1, wt2, attn_l2, attn_r2,
                                           feat8, el4, er4, mlist, mcnt, N_NODES);
  k_agg<1,1,0><<<BB*LL, 128, 0, stream>>>(feat8, el4, er4, b2, offs, csr,
                                          nid, nullptr, nullptr,
                                          ent_emb, rel_emb, glob, sht,
                                          s_tem, r_tem, out);
}